// Round 10
// baseline (4080.139 us; speedup 1.0000x reference)
//
#include <hip/hip_runtime.h>
#include <stdint.h>

#define NBATCH 32
#define NPTS   65536
#define MCENT  2048
#define BPB    8                 // blocks per batch (R5 proven topology)
#define THREADS 1024
#define CHUNK  (NPTS / BPB)      // 8192 points per block
#define WPT    (CHUNK / THREADS) // 8 points per thread
#define NWAVE  (THREADS / 64)    // 16 waves
#define GPW    2                 // groups (half-waves) per wave
#define NGRP   (NWAVE * GPW)     // 32 groups per block (256 pts each)
#define TMAX   64                // max centers selected per sync round

typedef unsigned long long u64;
typedef uint32_t u32;

static __device__ __forceinline__ u32 fbits(float f) { union { float f; u32 u; } c; c.f = f; return c.u; }
static __device__ __forceinline__ float bitsf(u32 u) { union { u32 u; float f; } c; c.u = u; return c.f; }

// wave-wide max of nonneg u32 via DPP row reduce (proven R4/R5);
// bound_ctrl=true -> invalid sources read 0 (identity for nonneg max).
static __device__ __forceinline__ u32 wave_max_u32(u32 v) {
#define STEP(CTRL) { const u32 o = (u32)__builtin_amdgcn_update_dpp(0, (int)v, CTRL, 0xF, 0xF, true); v = o > v ? o : v; }
    STEP(0x111) // row_shr:1
    STEP(0x112) // row_shr:2
    STEP(0x114) // row_shr:4
    STEP(0x118) // row_shr:8
    STEP(0x142) // row_bcast15
    STEP(0x143) // row_bcast31
#undef STEP
    return (u32)__builtin_amdgcn_readlane((int)v, 63);
}

// Multi-step FPS, R5 skeleton (single loop-top-adjacent barrier per round;
// best proven 2055 us) + REPLICATED SELECTION:
//   wave 0 polls the global pool, copies the POOLW words into LDS, then
//   ALL 16 waves replicate the pool-FPS selection from LDS. Each wave
//   derives the identical winner sequence (DPP/ballot/shfl on identical
//   data are deterministic) and folds its OWN 8-point pd update into the
//   selection loop per winner — Phase A vanishes from the serial chain
//   and no winner broadcast exists at all.
// Producer-consumer overlap (R6/R8/R9) is abandoned: spin/sleep consumers
// cost more than they hide; s_barrier parks waves for free.
//
// Global pool protocol (proven R2..R9, unchanged):
//   word = val_bits[63:32] | (idx^0xFFFF)[31:16] | sync_tag[15:0]
//   key order (val desc, idx asc) == jnp.argmax first-occurrence semantics.
//   Tags: poison 0xAA.. -> 0xAAAA, zero -> 0; s in [1,2047] never aliases.
//   Parity reuse safe (transitive): a block publishes s+1 only after its
//   waves finished selection(s) (they publish at loop top), which required
//   wave0's poll(s) complete, which required every peer published s, which
//   required that peer banked round s-1. LDS pool reuse safe by the same
//   chain: wave0 copies pool(s+1) only after poll(s+1) completes, which
//   requires its own waves published s+1, i.e. finished reading pool(s).
//
// Exactness: selection code is verbatim R5 (tau rule: accept iff value
// strictly > max of group TOPK-th values; first-occurrence tie-breaks;
// distance chain subs, then fma(dz,dz, fma(dx,dx, mul(dy,dy))),
// chronological fminf). Each wave applies winners in selection order ==
// R5's Phase-A order -> bit-identical pd trajectories.

template<int TOPK>
__global__ __launch_bounds__(THREADS, 1) void fps_kernel(
    const float* __restrict__ xyz,      // [NBATCH, NPTS, 3] fp32
    float* __restrict__ out,            // [NBATCH, MCENT, 3] fp32
    u64* __restrict__ slots)
{
    constexpr int POOLW = BPB * NGRP * TOPK;   // words per batch per parity
    constexpr int WPL   = POOLW / 64;          // words per lane

    const int t = threadIdx.x;
    const int b = blockIdx.x >> 3;   // batch (proven mapping)
    const int j = blockIdx.x & 7;    // block-within-batch
    const float* base = xyz + (size_t)b * NPTS * 3;
    const int p0 = j * CHUNK;
    const int wave = t >> 6;
    const int lane = t & 63;

    // coords + running min-dist live in registers
    float px[WPT], py[WPT], pz[WPT], pd[WPT];
#pragma unroll
    for (int q = 0; q < WPT; ++q) {
        const int p = p0 + q * THREADS + t;
        px[q] = base[(size_t)p * 3 + 0];
        py[q] = base[(size_t)p * 3 + 1];
        pz[q] = base[(size_t)p * 3 + 2];
        pd[q] = 1e10f;
    }

    __shared__ u64 pool[POOLW];    // round's pool, copied by wave 0

    if (t == 0 && j == 0) {
        float* o = out + (size_t)b * MCENT * 3;
        o[0] = base[0]; o[1] = base[1]; o[2] = base[2];
    }

    // initial center applied by all waves directly from registers
    {
        const float cx = base[0], cy = base[1], cz = base[2];
#pragma unroll
        for (int q = 0; q < WPT; ++q) {
            const float dx = __fsub_rn(px[q], cx);
            const float dy = __fsub_rn(py[q], cy);
            const float dz = __fsub_rn(pz[q], cz);
            const float s2 = __fmaf_rn(dz, dz,
                             __fmaf_rn(dx, dx,
                             __fmul_rn(dy, dy)));
            pd[q] = fminf(pd[q], s2);
        }
    }

    int C = 1;  // centers accounted (uniform across all waves/blocks)
    for (int s = 1; ; ++s) {
        // ---- per-lane top-TOPK keys over its 8 points (sorted insert) ----
        u64 k1 = 0, k2 = 0, k3 = 0;
#pragma unroll
        for (int q = 0; q < WPT; ++q) {
            const u64 kk = ((u64)fbits(pd[q]) << 16)
                         | (u64)(0xFFFFu ^ (u32)(p0 + q * THREADS + t));
            if (kk > k1)      { k3 = k2; k2 = k1; k1 = kk; }
            else if (kk > k2) { k3 = k2; k2 = kk; }
            else if (kk > k3) { k3 = kk; }
        }
        // ---- half-wave top-TOPK butterfly (5 xor levels, 32 lanes) ----
#pragma unroll
        for (int m = 1; m <= 16; m <<= 1) {
            const u64 o1 = __shfl_xor(k1, m);
            const u64 o2 = __shfl_xor(k2, m);
            if constexpr (TOPK == 2) {
                if (o1 > k1) { k2 = (k1 > o2) ? k1 : o2; k1 = o1; }
                else         { k2 = (k2 > o1) ? k2 : o1; }
            } else {
                const u64 o3 = __shfl_xor(k3, m);
                // merge sorted triples (k1>=k2>=k3), (o1>=o2>=o3) -> top-3
                u64 m1, m2, m3;
                if (o1 > k1) {
                    m1 = o1;
                    if (o2 > k1) { m2 = o2; m3 = (o3 > k1) ? o3 : k1; }
                    else         { m2 = k1; m3 = (o2 > k2) ? o2 : k2; }
                } else {
                    m1 = k1;
                    if (o1 > k2) { m2 = o1; m3 = (o2 > k2) ? o2 : k2; }
                    else         { m2 = k2; m3 = (o1 > k3) ? o1 : k3; }
                }
                k1 = m1; k2 = m2; k3 = m3;
            }
        }

        u64* const bb = slots + ((size_t)(s & 1) * NBATCH + b) * POOLW;
        const u32 tag = (u32)s & 0xFFFFu;

        // ---- publish: first lane of each half-wave stores TOPK words ----
        if ((lane & 31) == 0) {
            const int g = wave * GPW + (lane >> 5);     // group id 0..NGRP-1
            u64* const gw = &bb[j * (NGRP * TOPK) + g * TOPK];
            __hip_atomic_store(&gw[0], (k1 << 16) | tag,
                               __ATOMIC_RELAXED, __HIP_MEMORY_SCOPE_AGENT);
            __hip_atomic_store(&gw[1], (k2 << 16) | tag,
                               __ATOMIC_RELAXED, __HIP_MEMORY_SCOPE_AGENT);
            if constexpr (TOPK == 3)
                __hip_atomic_store(&gw[2], (k3 << 16) | tag,
                                   __ATOMIC_RELAXED, __HIP_MEMORY_SCOPE_AGENT);
        }

        if (wave == 0) {
            // ---- poll: WPL coalesced words/lane until all carry tag s ----
            u64 w[WPL]; int ok;
            do {
#pragma unroll
                for (int r = 0; r < WPL; ++r)
                    w[r] = __hip_atomic_load(&bb[lane + 64 * r],
                                             __ATOMIC_RELAXED, __HIP_MEMORY_SCOPE_AGENT);
                ok = 1;
#pragma unroll
                for (int r = 0; r < WPL; ++r)
                    ok &= ((u32)(w[r] & 0xFFFFull) == tag);
            } while (!__all(ok));
            // ---- stage pool into LDS for all waves ----
#pragma unroll
            for (int r = 0; r < WPL; ++r)
                pool[lane + 64 * r] = w[r];
        }
        __syncthreads();   // pool[] valid for everyone (single barrier/round)

        // ---- ALL waves: replicated selection from the LDS pool ----
        u32 pv[WPL], pi[WPL];
        float ex[WPL], ey[WPL], ez[WPL];
#pragma unroll
        for (int r = 0; r < WPL; ++r) {
            const u64 w = pool[lane + 64 * r];
            pv[r] = (u32)(w >> 32);
            pi[r] = ((u32)w >> 16) & 0xFFFFu;
            const int gi = (int)(0xFFFFu ^ pi[r]);   // global point idx
            ex[r] = base[(size_t)gi * 3 + 0];
            ey[r] = base[(size_t)gi * 3 + 1];
            ez[r] = base[(size_t)gi * 3 + 2];
        }

        // tau = max over group-LAST (TOPK-th) entries. Word index is
        // lane + 64*r -> rank = (lane%TOPK + (64%TOPK)*r) % TOPK.
        u32 tl = 0;
#pragma unroll
        for (int r = 0; r < WPL; ++r) {
            const int rank = ((lane % TOPK) + (64 % TOPK) * r) % TOPK;
            if (rank == TOPK - 1) tl = pv[r] > tl ? pv[r] : tl;
        }
        const u32 tauv = wave_max_u32(tl);

        // ---- pool-FPS: exact multi-step selection (verbatim R5 logic),
        //      own-pd update folded in per winner ----
        int tc = 0;
        while (1) {
            u32 lv = 0;
#pragma unroll
            for (int r = 0; r < WPL; ++r) lv = pv[r] > lv ? pv[r] : lv;
            const u32 vmax = wave_max_u32(lv);
            // step >=2 valid only if winner VALUE strictly beats tau
            if (tc > 0 && vmax <= tauv) break;

            // per-lane best inv among entries matching vmax (0 = none)
            u32 ic = 0;
#pragma unroll
            for (int r = 0; r < WPL; ++r)
                ic = (pv[r] == vmax && pi[r] + 1u > ic) ? pi[r] + 1u : ic;
            const u64 bal = __ballot(ic != 0);
            u32 winv; int ol;
            if (__popcll(bal) == 1) {
                // single owner lane: local tie-break already in ic
                ol = (int)__ffsll((long long)bal) - 1;
                winv = __shfl(ic, ol) - 1u;
            } else {
                // exact cross-lane tie-break: smallest global idx
                winv = wave_max_u32(ic) - 1u;
                int m = 0;
#pragma unroll
                for (int r = 0; r < WPL; ++r)
                    m |= (pv[r] == vmax) & (pi[r] == winv);
                ol = (int)__ffsll((long long)__ballot(m)) - 1;
            }

            // owner entry -> winner coords to all lanes
            float sx = 0.f, sy = 0.f, sz = 0.f;
#pragma unroll
            for (int r = 0; r < WPL; ++r) {
                const int m = (pv[r] == vmax) & (pi[r] == winv);
                sx = m ? ex[r] : sx;
                sy = m ? ey[r] : sy;
                sz = m ? ez[r] : sz;
            }
            const float wx = __shfl(sx, ol);
            const float wy = __shfl(sy, ol);
            const float wz = __shfl(sz, ol);

            // out-write (fire-and-forget, no fences anywhere -> free)
            if (wave == 0 && lane == 0 && j == 0) {
                float* o = out + ((size_t)b * MCENT + (C + tc)) * 3;
                o[0] = wx; o[1] = wy; o[2] = wz;
            }

            // own-pd update, chronological fminf (== R5 Phase-A order)
#pragma unroll
            for (int q = 0; q < WPT; ++q) {
                const float dx = __fsub_rn(px[q], wx);
                const float dy = __fsub_rn(py[q], wy);
                const float dz = __fsub_rn(pz[q], wz);
                const float s2 = __fmaf_rn(dz, dz,
                                 __fmaf_rn(dx, dx,
                                 __fmul_rn(dy, dy)));
                pd[q] = fminf(pd[q], s2);
            }

            ++tc;
            if (C + tc >= MCENT || tc >= TMAX) break;

            // min-update all pool entries vs winner (bit-exact chain);
            // winner's own entry sinks to 0 automatically
#pragma unroll
            for (int r = 0; r < WPL; ++r) {
                const float dx = __fsub_rn(ex[r], wx);
                const float dy = __fsub_rn(ey[r], wy);
                const float dz = __fsub_rn(ez[r], wz);
                const float s2 = __fmaf_rn(dz, dz,
                                 __fmaf_rn(dx, dx,
                                 __fmul_rn(dy, dy)));
                pv[r] = fbits(fminf(bitsf(pv[r]), s2));
            }
        }

        C += tc;           // identical in every wave of every block
        if (C >= MCENT) break;
    }
}

extern "C" void kernel_launch(void* const* d_in, const int* in_sizes, int n_in,
                              void* d_out, int out_size, void* d_ws, size_t ws_size,
                              hipStream_t stream) {
    const float* xyz = (const float*)d_in[0];
    float* out = (float*)d_out;
    u64* slots = (u64*)d_ws;

    // top-3 pool needs 2 parity x 32 batch x 768 words x 8 B = 384 KiB
    const size_t need3 = 2ull * NBATCH * (BPB * NGRP * 3) * sizeof(u64);
    if (ws_size >= need3) {
        fps_kernel<3><<<dim3(NBATCH * BPB), dim3(THREADS), 0, stream>>>(xyz, out, slots);
    } else {
        // TOPK=2 fallback (256 KiB)
        fps_kernel<2><<<dim3(NBATCH * BPB), dim3(THREADS), 0, stream>>>(xyz, out, slots);
    }
}

// Round 11
// 2086.590 us; speedup vs baseline: 1.9554x; 1.9554x over previous
//
#include <hip/hip_runtime.h>
#include <stdint.h>

#define NBATCH 32
#define NPTS   65536
#define MCENT  2048
#define BPB    8                 // blocks per batch (R5 proven topology)
#define THREADS 1024
#define CHUNK  (NPTS / BPB)      // 8192 points per block
#define WPT    (CHUNK / THREADS) // 8 points per thread
#define NPAIR  (WPT / 2)         // 4 float2 pairs per thread
#define NWAVE  (THREADS / 64)    // 16 waves
#define GPW    2                 // groups (half-waves) per wave
#define NGRP   (NWAVE * GPW)     // 32 groups per block (256 pts each)
#define TMAX   64                // max centers selected per sync round

typedef unsigned long long u64;
typedef uint32_t u32;
typedef float v2f __attribute__((ext_vector_type(2)));

static __device__ __forceinline__ u32 fbits(float f) { union { float f; u32 u; } c; c.f = f; return c.u; }
static __device__ __forceinline__ float bitsf(u32 u) { union { u32 u; float f; } c; c.u = u; return c.f; }

// wave-wide max of nonneg u32 via DPP row reduce (proven R4/R5);
// bound_ctrl=true -> invalid sources read 0 (identity for nonneg max).
static __device__ __forceinline__ u32 wave_max_u32(u32 v) {
#define STEP(CTRL) { const u32 o = (u32)__builtin_amdgcn_update_dpp(0, (int)v, CTRL, 0xF, 0xF, true); v = o > v ? o : v; }
    STEP(0x111) // row_shr:1
    STEP(0x112) // row_shr:2
    STEP(0x114) // row_shr:4
    STEP(0x118) // row_shr:8
    STEP(0x142) // row_bcast15
    STEP(0x143) // row_bcast31
#undef STEP
    return (u32)__builtin_amdgcn_readlane((int)v, 63);
}

// Multi-step FPS with a published candidate pool — EXACT R5 champion
// skeleton (2055 us) with ONE change: Phase A distance math on float2
// ext-vectors (__builtin_elementwise_fma, plain C++ ops) so clang emits
// gfx950 packed fp32 (v_pk_add/mul/fma_f32): ~8 issue slots per 2 points
// vs 14 scalar. v_pk_* perform the identical IEEE-RN op per half; the
// per-point chain (subs, then fma(dz,dz, fma(dx,dx, mul(dy,dy)))) and
// chronological fminf order are unchanged -> bit-identical results.
//
// Failed-structure ledger (do not revisit): hot-spin consume (R6, 2.4x:
// spinning waves steal issue from the serial critical path — s_barrier
// parks waves for free); 2-blocks/CU TLP (R7, null: duration = per-batch
// serial latency chain, co-residency can't shorten it); sleep-consume
// (R9, +14%: wake granularity + residual issue traffic exceed the ~1us
// hidden); replicated selection (R10, 2x: x16 VALU work, issue-bound).
//
// Pool protocol (proven R2..R5):
//   word = val_bits[63:32] | (idx^0xFFFF)[31:16] | sync_tag[15:0]
//   key order (val desc, idx asc) == jnp.argmax first-occurrence semantics.
//   Tags: poison 0xAA.. -> 0xAAAA, zero -> 0; s in [1,2047] never aliases.
//   Parity reuse safe: a block overwrites parity-p words at round s+2 only
//   after observing all round-s+1 tags; a peer publishes s+1 only after its
//   round-s poll banked all round-s words in registers.
//
// Exactness (every block replicates the identical pool computation):
//   step 1: pool holds every group's max -> pool argmax == global argmax.
//   step t>=2: any point NOT in the pool is <= its group's published
//   TOPK-th value <= tau = max over groups of TOPK-th values (true dists
//   only decrease). Accept a winner iff its VALUE strictly > tau (hidden
//   points can then neither beat nor tie it); else bail and re-sync.

template<int TOPK>
__global__ __launch_bounds__(THREADS, 1) void fps_kernel(
    const float* __restrict__ xyz,      // [NBATCH, NPTS, 3] fp32
    float* __restrict__ out,            // [NBATCH, MCENT, 3] fp32
    u64* __restrict__ slots)
{
    constexpr int POOLW = BPB * NGRP * TOPK;   // words per batch per parity
    constexpr int WPL   = POOLW / 64;          // words per lane (wave 0)

    const int t = threadIdx.x;
    const int b = blockIdx.x >> 3;   // batch (proven mapping)
    const int j = blockIdx.x & 7;    // block-within-batch
    const float* base = xyz + (size_t)b * NPTS * 3;
    const int p0 = j * CHUNK;
    const int wave = t >> 6;
    const int lane = t & 63;

    // coords packed as float2 pairs (points 2q, 2q+1); pd stays scalar
    v2f px2[NPAIR], py2[NPAIR], pz2[NPAIR];
    float pd[WPT];
#pragma unroll
    for (int q = 0; q < WPT; ++q) {
        const int p = p0 + q * THREADS + t;
        px2[q >> 1][q & 1] = base[(size_t)p * 3 + 0];
        py2[q >> 1][q & 1] = base[(size_t)p * 3 + 1];
        pz2[q >> 1][q & 1] = base[(size_t)p * 3 + 2];
        pd[q] = 1e10f;
    }

    __shared__ float wcx[TMAX], wcy[TMAX], wcz[TMAX]; // winners of last round
    __shared__ int   wcnt;

    if (t == 0) {
        const float cx = base[0], cy = base[1], cz = base[2];
        wcx[0] = cx; wcy[0] = cy; wcz[0] = cz; wcnt = 1;
        if (j == 0) {
            float* o = out + (size_t)b * MCENT * 3;
            o[0] = cx; o[1] = cy; o[2] = cz;
        }
    }

    int C = 0;  // centers accounted (uniform across all blocks)
    for (int s = 1; ; ++s) {
        __syncthreads();                 // wcnt / wc* of previous round valid
        const int tn = wcnt;
        C += tn;
        if (C >= MCENT) break;

        // ---- Phase A: packed-f32 min-dist update vs the tn new centers ----
        for (int tt = 0; tt < tn; ++tt) {
            const float cx = wcx[tt], cy = wcy[tt], cz = wcz[tt];
            const v2f cx2 = { cx, cx }, cy2 = { cy, cy }, cz2 = { cz, cz };
#pragma unroll
            for (int q = 0; q < NPAIR; ++q) {
                const v2f dx2 = px2[q] - cx2;            // v_pk_add (neg)
                const v2f dy2 = py2[q] - cy2;
                const v2f dz2 = pz2[q] - cz2;
                const v2f t0  = dy2 * dy2;               // v_pk_mul
                const v2f t1  = __builtin_elementwise_fma(dx2, dx2, t0);
                const v2f t2  = __builtin_elementwise_fma(dz2, dz2, t1);
                pd[2 * q + 0] = fminf(pd[2 * q + 0], t2.x);
                pd[2 * q + 1] = fminf(pd[2 * q + 1], t2.y);
            }
        }

        // ---- per-lane top-TOPK keys over its 8 points (sorted insert) ----
        u64 k1 = 0, k2 = 0, k3 = 0;
#pragma unroll
        for (int q = 0; q < WPT; ++q) {
            const u64 kk = ((u64)fbits(pd[q]) << 16)
                         | (u64)(0xFFFFu ^ (u32)(p0 + q * THREADS + t));
            if (kk > k1)      { k3 = k2; k2 = k1; k1 = kk; }
            else if (kk > k2) { k3 = k2; k2 = kk; }
            else if (kk > k3) { k3 = kk; }
        }
        // ---- half-wave top-TOPK butterfly (5 xor levels, 32 lanes) ----
#pragma unroll
        for (int m = 1; m <= 16; m <<= 1) {
            const u64 o1 = __shfl_xor(k1, m);
            const u64 o2 = __shfl_xor(k2, m);
            if constexpr (TOPK == 2) {
                if (o1 > k1) { k2 = (k1 > o2) ? k1 : o2; k1 = o1; }
                else         { k2 = (k2 > o1) ? k2 : o1; }
            } else {
                const u64 o3 = __shfl_xor(k3, m);
                // merge sorted triples (k1>=k2>=k3), (o1>=o2>=o3) -> top-3
                u64 m1, m2, m3;
                if (o1 > k1) {
                    m1 = o1;
                    if (o2 > k1) { m2 = o2; m3 = (o3 > k1) ? o3 : k1; }
                    else         { m2 = k1; m3 = (o2 > k2) ? o2 : k2; }
                } else {
                    m1 = k1;
                    if (o1 > k2) { m2 = o1; m3 = (o2 > k2) ? o2 : k2; }
                    else         { m2 = k2; m3 = (o1 > k3) ? o1 : k3; }
                }
                k1 = m1; k2 = m2; k3 = m3;
            }
        }

        u64* const bb = slots + ((size_t)(s & 1) * NBATCH + b) * POOLW;
        const u32 tag = (u32)s & 0xFFFFu;

        // ---- publish: first lane of each half-wave stores TOPK words ----
        if ((lane & 31) == 0) {
            const int g = wave * GPW + (lane >> 5);     // group id 0..31
            u64* const gw = &bb[j * (NGRP * TOPK) + g * TOPK];
            __hip_atomic_store(&gw[0], (k1 << 16) | tag,
                               __ATOMIC_RELAXED, __HIP_MEMORY_SCOPE_AGENT);
            __hip_atomic_store(&gw[1], (k2 << 16) | tag,
                               __ATOMIC_RELAXED, __HIP_MEMORY_SCOPE_AGENT);
            if constexpr (TOPK == 3)
                __hip_atomic_store(&gw[2], (k3 << 16) | tag,
                                   __ATOMIC_RELAXED, __HIP_MEMORY_SCOPE_AGENT);
        }
        // waves 1..15 park at the loop-top barrier; wave 0 polls.

        if (wave == 0) {
            // ---- poll: WPL coalesced words/lane until all carry tag s ----
            u64 w[WPL]; int ok;
            do {
#pragma unroll
                for (int r = 0; r < WPL; ++r)
                    w[r] = __hip_atomic_load(&bb[lane + 64 * r],
                                             __ATOMIC_RELAXED, __HIP_MEMORY_SCOPE_AGENT);
                ok = 1;
#pragma unroll
                for (int r = 0; r < WPL; ++r)
                    ok &= ((u32)(w[r] & 0xFFFFull) == tag);
            } while (!__all(ok));

            // ---- unpack pool: split (val, inv-idx) + gather coords ----
            u32 pv[WPL], pi[WPL];
            float ex[WPL], ey[WPL], ez[WPL];
#pragma unroll
            for (int r = 0; r < WPL; ++r) {
                pv[r] = (u32)(w[r] >> 32);
                pi[r] = ((u32)w[r] >> 16) & 0xFFFFu;
                const int gi = (int)(0xFFFFu ^ pi[r]);   // global point idx
                ex[r] = base[(size_t)gi * 3 + 0];
                ey[r] = base[(size_t)gi * 3 + 1];
                ez[r] = base[(size_t)gi * 3 + 2];
            }

            // tau = max over group-LAST (TOPK-th) entries. Word index is
            // lane + 64*r -> rank = (lane%TOPK + (64%TOPK)*r) % TOPK.
            u32 tl = 0;
#pragma unroll
            for (int r = 0; r < WPL; ++r) {
                const int rank = ((lane % TOPK) + (64 % TOPK) * r) % TOPK;
                if (rank == TOPK - 1) tl = pv[r] > tl ? pv[r] : tl;
            }
            const u32 tauv = wave_max_u32(tl);

            // ---- pool-FPS: exact multi-step selection ----
            int tc = 0;
            while (1) {
                u32 lv = 0;
#pragma unroll
                for (int r = 0; r < WPL; ++r) lv = pv[r] > lv ? pv[r] : lv;
                const u32 vmax = wave_max_u32(lv);
                // step >=2 valid only if winner VALUE strictly beats tau
                if (tc > 0 && vmax <= tauv) break;

                // per-lane best inv among entries matching vmax (0 = none)
                u32 ic = 0;
#pragma unroll
                for (int r = 0; r < WPL; ++r)
                    ic = (pv[r] == vmax && pi[r] + 1u > ic) ? pi[r] + 1u : ic;
                const u64 bal = __ballot(ic != 0);
                u32 winv; int ol;
                if (__popcll(bal) == 1) {
                    // single owner lane: local tie-break already in ic
                    ol = (int)__ffsll((long long)bal) - 1;
                    winv = __shfl(ic, ol) - 1u;
                } else {
                    // exact cross-lane tie-break: smallest global idx
                    winv = wave_max_u32(ic) - 1u;
                    int m = 0;
#pragma unroll
                    for (int r = 0; r < WPL; ++r)
                        m |= (pv[r] == vmax) & (pi[r] == winv);
                    ol = (int)__ffsll((long long)__ballot(m)) - 1;
                }

                // owner entry -> winner coords to all lanes
                float sx = 0.f, sy = 0.f, sz = 0.f;
#pragma unroll
                for (int r = 0; r < WPL; ++r) {
                    const int m = (pv[r] == vmax) & (pi[r] == winv);
                    sx = m ? ex[r] : sx;
                    sy = m ? ey[r] : sy;
                    sz = m ? ez[r] : sz;
                }
                const float wx = __shfl(sx, ol);
                const float wy = __shfl(sy, ol);
                const float wz = __shfl(sz, ol);

                if (lane == 0) {
                    wcx[tc] = wx; wcy[tc] = wy; wcz[tc] = wz;
                    if (j == 0) {
                        float* o = out + ((size_t)b * MCENT + (C + tc)) * 3;
                        o[0] = wx; o[1] = wy; o[2] = wz;
                    }
                }
                ++tc;
                if (C + tc >= MCENT || tc >= TMAX) break;

                // min-update all entries vs winner (bit-exact chain);
                // winner's own entry sinks to 0 automatically
#pragma unroll
                for (int r = 0; r < WPL; ++r) {
                    const float dx = __fsub_rn(ex[r], wx);
                    const float dy = __fsub_rn(ey[r], wy);
                    const float dz = __fsub_rn(ez[r], wz);
                    const float s2 = __fmaf_rn(dz, dz,
                                     __fmaf_rn(dx, dx,
                                     __fmul_rn(dy, dy)));
                    pv[r] = fbits(fminf(bitsf(pv[r]), s2));
                }
            }
            if (lane == 0) wcnt = tc;
        }
    }
}

extern "C" void kernel_launch(void* const* d_in, const int* in_sizes, int n_in,
                              void* d_out, int out_size, void* d_ws, size_t ws_size,
                              hipStream_t stream) {
    const float* xyz = (const float*)d_in[0];
    float* out = (float*)d_out;
    u64* slots = (u64*)d_ws;

    // top-3 pool needs 2 parity x 32 batch x 768 words x 8 B = 384 KiB
    const size_t need3 = 2ull * NBATCH * (BPB * NGRP * 3) * sizeof(u64);
    if (ws_size >= need3) {
        fps_kernel<3><<<dim3(NBATCH * BPB), dim3(THREADS), 0, stream>>>(xyz, out, slots);
    } else {
        // TOPK=2 fallback (256 KiB)
        fps_kernel<2><<<dim3(NBATCH * BPB), dim3(THREADS), 0, stream>>>(xyz, out, slots);
    }
}